// Round 10
// baseline (283.389 us; speedup 1.0000x reference)
//
#include <hip/hip_runtime.h>
#include <stdint.h>

typedef _Float16 f16x8 __attribute__((ext_vector_type(8)));
typedef float f32x4 __attribute__((ext_vector_type(4)));

__device__ __forceinline__ unsigned short f2h(float f) {
  _Float16 h = (_Float16)f;
  return __builtin_bit_cast(unsigned short, h);
}

#if __has_builtin(__builtin_amdgcn_global_load_lds)
#define HAVE_GLL 1
__device__ __forceinline__ void gload_lds16(const void* g, void* l) {
  auto gp = reinterpret_cast<const __attribute__((address_space(1))) void*>(
      reinterpret_cast<uintptr_t>(g));
  auto lp = reinterpret_cast<__attribute__((address_space(3))) void*>(
      reinterpret_cast<uintptr_t>(l));
  __builtin_amdgcn_global_load_lds(gp, lp, 16, 0, 0);
}
#else
#define HAVE_GLL 0
#endif

// ---------------- fused setup ----------------
__device__ __forceinline__ void transpose_core(const float* in, unsigned short* out,
                                               int R, int C, int c0, int r0) {
  __shared__ float t[32][33];
  int tx = threadIdx.x & 31, ty = threadIdx.x >> 5;  // 32 x 8
#pragma unroll
  for (int i = 0; i < 32; i += 8)
    t[ty + i][tx] = in[(long)(r0 + ty + i) * C + (c0 + tx)];
  __syncthreads();
#pragma unroll
  for (int i = 0; i < 32; i += 8)
    out[(long)(c0 + ty + i) * R + (r0 + tx)] = f2h(t[tx][ty + i]);
}

// grid (128,16,5): z=0 Wq^T, z=1 Wk^T ([512,4096]->[4096,512]);
// z=2 Wu [4096,512]->[512,4096]; z=3 convert x; z=4 convert Wv.
__global__ __launch_bounds__(256) void k_setup(
    const float* __restrict__ x, const float* __restrict__ Wq, const float* __restrict__ Wk,
    const float* __restrict__ Wv, const float* __restrict__ Wu,
    unsigned short* __restrict__ Xh, unsigned short* __restrict__ Wqt,
    unsigned short* __restrict__ Wkt, unsigned short* __restrict__ Wvh,
    unsigned short* __restrict__ Wut) {
  int z = blockIdx.z;
  if (z == 0) {
    transpose_core(Wq, Wqt, 512, 4096, blockIdx.x * 32, blockIdx.y * 32);
  } else if (z == 1) {
    transpose_core(Wk, Wkt, 512, 4096, blockIdx.x * 32, blockIdx.y * 32);
  } else if (z == 2) {
    transpose_core(Wu, Wut, 4096, 512, blockIdx.y * 32, blockIdx.x * 32);
  } else {
    const float* in = (z == 3) ? x : Wv;
    unsigned short* out = (z == 3) ? Xh : Wvh;
    int i = (blockIdx.y * 128 + blockIdx.x) * 256 + threadIdx.x;
    float4 v = reinterpret_cast<const float4*>(in)[i];
    ushort4 o;
    o.x = f2h(v.x); o.y = f2h(v.y); o.z = f2h(v.z); o.w = f2h(v.w);
    reinterpret_cast<ushort4*>(out)[i] = o;
  }
}

// ---------------- GEMM core: C[M,N] = A[M,K] * B[N,K]^T ----------------
// 128x128 tile, BK=64, 256 threads (4 waves, 2x2 of 64x64), mfma 16x16x32 f16.
// LDS XOR-swizzled at 16B granularity; staging via global_load_lds(16B).
// LDS passed in (shared across any inlined uses). ONE instantiation per kernel
// (dual instantiation inflated VGPR 64->88 and cost ~15% — seen R8/R9).
// OUT: 1 fp16 store, 2 fp32 atomicAdd.
// BVU: B rows live in VUt[h*512+e][b*1024+j]; staging addr uses global k
// kk = kbase+k0: e*ldb + (kk>>10)*2097152 + (kk&1023).
template <int OUT, int BVU>
__device__ __forceinline__ void gemm_core(unsigned short* __restrict__ As,
                                          unsigned short* __restrict__ Bs,
                                          const unsigned short* __restrict__ A,
                                          const unsigned short* __restrict__ B,
                                          void* __restrict__ Cv, int K, int lda, int ldb,
                                          int ldc, long coff, int m0, int n0, int kbase) {
  int tid = threadIdx.x;
  int wid = tid >> 6, lane = tid & 63;
  int wm = (wid >> 1) * 64, wn = (wid & 1) * 64;
  int rq = lane >> 4, rl = lane & 15;

  f32x4 acc[4][4];
#pragma unroll
  for (int i = 0; i < 4; ++i)
#pragma unroll
    for (int j = 0; j < 4; ++j) acc[i][j] = (f32x4){0.f, 0.f, 0.f, 0.f};

#if HAVE_GLL
  int cg = (lane & 7) ^ ((lane >> 3) & 7);  // permuted global chunk -> swizzled LDS
  int rl8 = lane >> 3;                      // row within 8-row group
#endif

  for (int k0 = 0; k0 < K; k0 += 64) {
    long bko;
    if (BVU) {
      int kk = kbase + k0;
      bko = (long)(kk >> 10) * 2097152 + (kk & 1023);
    } else {
      bko = k0;
    }
    __syncthreads();
#if HAVE_GLL
#pragma unroll
    for (int t = 0; t < 4; ++t) {
      int r = wid * 32 + t * 8;  // uniform slab base row
      gload_lds16(&A[(long)(m0 + r + rl8) * lda + k0 + cg * 8], &As[r * 64]);
      gload_lds16(&B[(long)(n0 + r + rl8) * ldb + bko + cg * 8], &Bs[r * 64]);
    }
#else
#pragma unroll
    for (int it = 0; it < 4; ++it) {
      int idx = tid + it * 256;
      int r = idx >> 3, c = idx & 7;
      int cs = c ^ (r & 7);
      *reinterpret_cast<uint4*>(&As[r * 64 + cs * 8]) =
          *reinterpret_cast<const uint4*>(&A[(long)(m0 + r) * lda + k0 + c * 8]);
      *reinterpret_cast<uint4*>(&Bs[r * 64 + cs * 8]) =
          *reinterpret_cast<const uint4*>(&B[(long)(n0 + r) * ldb + bko + c * 8]);
    }
#endif
    __syncthreads();
#pragma unroll
    for (int ks = 0; ks < 2; ++ks) {
      f16x8 af[4], bfr[4];
      int kc = ks * 4 + rq;
#pragma unroll
      for (int i = 0; i < 4; ++i) {
        int ra = wm + i * 16 + rl;
        af[i] = *reinterpret_cast<const f16x8*>(&As[ra * 64 + ((kc ^ (ra & 7)) << 3)]);
        int rb = wn + i * 16 + rl;
        bfr[i] = *reinterpret_cast<const f16x8*>(&Bs[rb * 64 + ((kc ^ (rb & 7)) << 3)]);
      }
#pragma unroll
      for (int i = 0; i < 4; ++i)
#pragma unroll
        for (int j = 0; j < 4; ++j)
          acc[i][j] = __builtin_amdgcn_mfma_f32_16x16x32_f16(af[i], bfr[j], acc[i][j], 0, 0, 0);
    }
  }

#pragma unroll
  for (int i = 0; i < 4; ++i)
#pragma unroll
    for (int j = 0; j < 4; ++j)
#pragma unroll
      for (int r = 0; r < 4; ++r) {
        int row = m0 + wm + i * 16 + rq * 4 + r;
        int col = n0 + wn + j * 16 + rl;
        float v = acc[i][j][r];
        if (OUT == 1)
          reinterpret_cast<unsigned short*>(Cv)[coff + (long)row * ldc + col] = f2h(v);
        else
          atomicAdd(&reinterpret_cast<float*>(Cv)[coff + (long)row * ldc + col], v);
      }
}

#define DECL_LDS \
  __shared__ unsigned short As[128 * 64]; \
  __shared__ unsigned short Bs[128 * 64];

// launch2: Q + K projections + Wvut, grid (8, 272). ONE gemm_core<1,0> call.
// w<256: z=w>>7 in {0:Q,1:K}, r=w&127: col-tile x=4c+(r&3) (head x/4 == XCD c),
//        y=r>>2. C[bt][hd] = X . W^T.
// w>=256 (w'=w-256<16): Wvut[h][e][k] = sum_d Wut[e][h*512+d]*Wvh[k][h*512+d],
//        h = c (8 heads on 8 XCDs), y=(w'>>2)&3, x=w'&3.
__global__ __launch_bounds__(256, 2) void k_gemm_qkw(
    const unsigned short* __restrict__ X, const unsigned short* __restrict__ Wqt,
    const unsigned short* __restrict__ Wkt, const unsigned short* __restrict__ Wvh,
    const unsigned short* __restrict__ Wut, unsigned short* __restrict__ Qb,
    unsigned short* __restrict__ Kb, unsigned short* __restrict__ Wvut) {
  DECL_LDS
  int c = blockIdx.x, w = blockIdx.y;
  const unsigned short *A, *B;
  unsigned short* C;
  int lda, ldb, ldc, m0, n0;
  long coff;
  if (w < 256) {
    int z = w >> 7, r = w & 127;
    int x = 4 * c + (r & 3), y = r >> 2;
    A = X; B = (z == 0) ? Wqt : Wkt; C = (z == 0) ? Qb : Kb;
    lda = 512; ldb = 512; ldc = 4096; coff = 0; m0 = y * 128; n0 = x * 128;
  } else {
    int wp = w - 256;
    A = Wut + c * 512; B = Wvh + c * 512; C = Wvut + (long)c * 262144;
    lda = 4096; ldb = 4096; ldc = 512; coff = 0;
    m0 = ((wp >> 2) & 3) * 128; n0 = (wp & 3) * 128;
  }
  gemm_core<1, 0>(As, Bs, A, B, C, 512, lda, ldb, ldc, coff, m0, n0, 0);
}

// launch3: S-gemm + VU-projection fused, grid (8, 384). ONE gemm_core<1,0> call.
// w<256: S: z = c + 8*(w>>6) (b=z>>3,h=z&7), t=w&63, y=t>>3, x=t&7.
//        P[b][i][h*1024+j] = K[b,i,h,:] . Q[b,j,h,:]  (ldc 8192).
// w>=256 (w'=w-256<128): VU^T: VUt[h*512+e][b*1024+j] = Wvut . X^T;
//        y=4c+(w'&3) (head y/4 == XCD c), x=w'>>2.
__global__ __launch_bounds__(256, 2) void k_gemm_sv(
    const unsigned short* __restrict__ X, const unsigned short* __restrict__ Qb,
    const unsigned short* __restrict__ Kb, const unsigned short* __restrict__ Wvut,
    unsigned short* __restrict__ Pb, unsigned short* __restrict__ VUt) {
  DECL_LDS
  int c = blockIdx.x, w = blockIdx.y;
  const unsigned short *A, *B;
  unsigned short* C;
  int lda, ldb, ldc, m0, n0;
  long coff;
  if (w < 256) {
    int z = c + 8 * (w >> 6), t = w & 63;
    int b = z >> 3, h = z & 7;
    long off = (long)b * 4194304 + h * 512;
    A = Kb + off; B = Qb + off; C = Pb;
    lda = 4096; ldb = 4096; ldc = 8192;
    coff = (long)b * 8388608 + h * 1024;
    m0 = (t >> 3) * 128; n0 = (t & 7) * 128;
  } else {
    int wp = w - 256;
    A = Wvut; B = X; C = VUt;
    lda = 512; ldb = 512; ldc = 4096; coff = 0;
    m0 = (4 * c + (wp & 3)) * 128; n0 = (wp >> 2) * 128;
  }
  gemm_core<1, 0>(As, Bs, A, B, C, 512, lda, ldb, ldc, coff, m0, n0, 0);
}

// O-final: out[b,i,e] += sum_kk Pb[b][i][kk] * VUt[(kk>>10)*512+e][b*1024+(kk&1023)].
// grid (8,64). Group g=(b,kchunk,ihalf): working set = P slab 2 MiB + VU slab
// 2 MiB = 4 MiB = one XCD L2; XCD g%8 matches where those k-chunks were written.
// atomicAdd into pre-zeroed fp32 out (4 adds/elem).
__global__ __launch_bounds__(256, 2) void k_gemm_out(
    const unsigned short* __restrict__ Pb, const unsigned short* __restrict__ VUt,
    float* __restrict__ out) {
  DECL_LDS
  int c = blockIdx.x, w = blockIdx.y;
  int g = c + 8 * (w >> 4);  // 0..31
  int r = w & 15;
  int b = g >> 3, kc = (g >> 1) & 3, ih = g & 1;
  int y = ih * 4 + (r >> 2);  // 0..7  (i-tile)
  int x = r & 3;              // 0..3  (e-tile)
  gemm_core<2, 1>(As, Bs, Pb + (long)b * 8388608 + kc * 2048, VUt + (long)b * 1024,
                  out, 2048, 8192, 4096, 512, (long)b * 524288, y * 128, x * 128,
                  kc * 2048);
}

// ---------------- softmax: one wave per 1024-chunk, P[b][i][h*1024+j] ----------------
// grid (8,1024): h = blockIdx.x (XCD-aligned with the S-gemm writer).
__global__ __launch_bounds__(256) void k_softmax_x(unsigned short* __restrict__ S) {
  int g = blockIdx.y * 4 + (threadIdx.x >> 6);
  int b = g >> 10, i = g & 1023;
  long base = (long)b * 8388608 + (long)i * 8192 + (long)blockIdx.x * 1024;
  int lane = threadIdx.x & 63;
  f16x8* p = reinterpret_cast<f16x8*>(S + base);
  f16x8 a = p[lane * 2], bb = p[lane * 2 + 1];
  float v[16];
#pragma unroll
  for (int q = 0; q < 8; ++q) { v[q] = (float)a[q]; v[8 + q] = (float)bb[q]; }
  float m = v[0];
#pragma unroll
  for (int q = 1; q < 16; ++q) m = fmaxf(m, v[q]);
#pragma unroll
  for (int o = 32; o; o >>= 1) m = fmaxf(m, __shfl_xor(m, o));
  float s = 0.f;
#pragma unroll
  for (int q = 0; q < 16; ++q) { v[q] = __expf(v[q] - m); s += v[q]; }
#pragma unroll
  for (int o = 32; o; o >>= 1) s += __shfl_xor(s, o);
  float inv = 1.0f / s;
  f16x8 oa, ob;
#pragma unroll
  for (int q = 0; q < 8; ++q) {
    oa[q] = (_Float16)(v[q] * inv);
    ob[q] = (_Float16)(v[8 + q] * inv);
  }
  p[lane * 2] = oa;
  p[lane * 2 + 1] = ob;
}

__global__ void k_sentinel(float* out, float v) { out[0] = v; }

extern "C" void kernel_launch(void* const* d_in, const int* in_sizes, int n_in,
                              void* d_out, int out_size, void* d_ws, size_t ws_size,
                              hipStream_t stream) {
  // setup_inputs dict order: x, Wk, Wq, Wv, Wu
  const float* x  = (const float*)d_in[0];
  const float* Wk = (const float*)d_in[1];
  const float* Wq = (const float*)d_in[2];
  const float* Wv = (const float*)d_in[3];
  const float* Wu = (const float*)d_in[4];
  float* out = (float*)d_out;

  const long SZ_X = 4096L * 512;
  const long SZ_W = 512L * 4096;
  const size_t NEED = 188743680;  // 180 MiB exactly (verified fits)

  if (ws_size < NEED) {
    hipMemsetAsync(d_out, 0, (size_t)out_size * 4, stream);
    k_sentinel<<<1, 1, 0, stream>>>(out, (float)ws_size);
    return;
  }

  char* p = (char*)d_ws;
  unsigned short* Xbf  = (unsigned short*)p; p += SZ_X * 2;          //  4 MiB
  unsigned short* Wqt  = (unsigned short*)p; p += SZ_W * 2;          //  4 MiB
  unsigned short* Wkt  = (unsigned short*)p; p += SZ_W * 2;          //  4 MiB
  unsigned short* Wut  = (unsigned short*)p; p += SZ_W * 2;          //  4 MiB
  unsigned short* Wvut = (unsigned short*)p; p += SZ_W * 2;          //  4 MiB [h][e][k]
  unsigned short* Qb   = (unsigned short*)p; p += 4096L * 4096 * 2;  // 32 MiB
  unsigned short* Kb   = (unsigned short*)p; p += 4096L * 4096 * 2;  // 32 MiB
  unsigned short* Pb   = (unsigned short*)p; p += 4096L * 8192 * 2;  // 64 MiB [b][i][h*1024+j]
  unsigned short* VUt  = (unsigned short*)p;                         // 32 MiB [h*512+e][b*1024+j]
  unsigned short* Wvh  = VUt;  // 4 MiB alias: consumed (launch2) before VUt written (launch3)

  // zero d_out early (final gemm atomicAdds into it)
  hipMemsetAsync(d_out, 0, (size_t)out_size * 4, stream);

  // ---- setup: Wq^T, Wk^T, Wu^T, convert x, convert Wv ----
  k_setup<<<dim3(128, 16, 5), 256, 0, stream>>>(x, Wq, Wk, Wv, Wu, Xbf, Wqt, Wkt, Wvh, Wut);

  // ---- Q/K projections + Wvut = Wu_h^T . Wv_h (per-head 512^3) ----
  k_gemm_qkw<<<dim3(8, 272), 256, 0, stream>>>(Xbf, Wqt, Wkt, Wvh, Wut, Qb, Kb, Wvut);

  // ---- S: P[b][i][h*1024+j] = K.Q^T  +  VU^T = Wvut . X^T (fused launch) ----
  k_gemm_sv<<<dim3(8, 384), 256, 0, stream>>>(Xbf, Qb, Kb, Wvut, Pb, VUt);

  // ---- softmax over each 1024-chunk of P, in place ----
  k_softmax_x<<<dim3(8, 1024), 256, 0, stream>>>(Pb);

  // ---- out = P . VU^T (strided-head B), L2-sized groups, atomicAdd ----
  k_gemm_out<<<dim3(8, 64), 256, 0, stream>>>(Pb, VUt, out);
}

// Round 11
// 263.241 us; speedup vs baseline: 1.0765x; 1.0765x over previous
//
#include <hip/hip_runtime.h>
#include <stdint.h>

typedef _Float16 f16x8 __attribute__((ext_vector_type(8)));
typedef float f32x4 __attribute__((ext_vector_type(4)));

__device__ __forceinline__ unsigned short f2h(float f) {
  _Float16 h = (_Float16)f;
  return __builtin_bit_cast(unsigned short, h);
}

#if __has_builtin(__builtin_amdgcn_global_load_lds)
#define HAVE_GLL 1
__device__ __forceinline__ void gload_lds16(const void* g, void* l) {
  auto gp = reinterpret_cast<const __attribute__((address_space(1))) void*>(
      reinterpret_cast<uintptr_t>(g));
  auto lp = reinterpret_cast<__attribute__((address_space(3))) void*>(
      reinterpret_cast<uintptr_t>(l));
  __builtin_amdgcn_global_load_lds(gp, lp, 16, 0, 0);
}
#else
#define HAVE_GLL 0
#endif

// ---------------- fused setup ----------------
__device__ __forceinline__ void transpose_core(const float* in, unsigned short* out,
                                               int R, int C, int c0, int r0) {
  __shared__ float t[32][33];
  int tx = threadIdx.x & 31, ty = threadIdx.x >> 5;  // 32 x 8
#pragma unroll
  for (int i = 0; i < 32; i += 8)
    t[ty + i][tx] = in[(long)(r0 + ty + i) * C + (c0 + tx)];
  __syncthreads();
#pragma unroll
  for (int i = 0; i < 32; i += 8)
    out[(long)(c0 + ty + i) * R + (r0 + tx)] = f2h(t[tx][ty + i]);
}

// grid (128,16,6): z=0 convert Wq (NO transpose: G-fold consumes in-major),
// z=1 convert Wk, z=2 transpose Wu [4096,512]->[512,4096], z=3 convert x,
// z=4 convert Wv, z=5 zero d_out (2M floats).
__global__ __launch_bounds__(256) void k_setup(
    const float* __restrict__ x, const float* __restrict__ Wq, const float* __restrict__ Wk,
    const float* __restrict__ Wv, const float* __restrict__ Wu,
    unsigned short* __restrict__ Xh, unsigned short* __restrict__ Wqf,
    unsigned short* __restrict__ Wkf, unsigned short* __restrict__ Wvh,
    unsigned short* __restrict__ Wut, float* __restrict__ out) {
  int z = blockIdx.z;
  if (z == 2) {
    transpose_core(Wu, Wut, 4096, 512, blockIdx.y * 32, blockIdx.x * 32);
  } else if (z == 5) {
    int i = (blockIdx.y * 128 + blockIdx.x) * 256 + threadIdx.x;
    reinterpret_cast<float4*>(out)[i] = (float4){0.f, 0.f, 0.f, 0.f};
  } else {
    const float* in = (z == 0) ? Wq : (z == 1) ? Wk : (z == 3) ? x : Wv;
    unsigned short* o = (z == 0) ? Wqf : (z == 1) ? Wkf : (z == 3) ? Xh : Wvh;
    int i = (blockIdx.y * 128 + blockIdx.x) * 256 + threadIdx.x;
    float4 v = reinterpret_cast<const float4*>(in)[i];
    ushort4 u;
    u.x = f2h(v.x); u.y = f2h(v.y); u.z = f2h(v.z); u.w = f2h(v.w);
    reinterpret_cast<ushort4*>(o)[i] = u;
  }
}

// ---------------- GEMM core: C[M,N] = A[M,K] * B[N,K]^T ----------------
// 128x128 tile, BK=64, 256 threads (4 waves, 2x2 of 64x64), mfma 16x16x32 f16.
// LDS XOR-swizzled at 16B granularity; staging via global_load_lds(16B).
// LDS passed in. ONE template instantiation per kernel, selection only via
// pointer/geometry args (dual instantiation inflated VGPR 64->88, -15%: R8/R9).
// OUT: 1 fp16 store, 2 fp32 atomicAdd.
// BVU: B rows live in VUt[h*512+e][b*1024+j]; staging addr uses global k
// kk = kbase+k0: e*ldb + (kk>>10)*2097152 + (kk&1023).
template <int OUT, int BVU>
__device__ __forceinline__ void gemm_core(unsigned short* __restrict__ As,
                                          unsigned short* __restrict__ Bs,
                                          const unsigned short* __restrict__ A,
                                          const unsigned short* __restrict__ B,
                                          void* __restrict__ Cv, int K, int lda, int ldb,
                                          int ldc, long coff, int m0, int n0, int kbase) {
  int tid = threadIdx.x;
  int wid = tid >> 6, lane = tid & 63;
  int wm = (wid >> 1) * 64, wn = (wid & 1) * 64;
  int rq = lane >> 4, rl = lane & 15;

  f32x4 acc[4][4];
#pragma unroll
  for (int i = 0; i < 4; ++i)
#pragma unroll
    for (int j = 0; j < 4; ++j) acc[i][j] = (f32x4){0.f, 0.f, 0.f, 0.f};

#if HAVE_GLL
  int cg = (lane & 7) ^ ((lane >> 3) & 7);  // permuted global chunk -> swizzled LDS
  int rl8 = lane >> 3;                      // row within 8-row group
#endif

  for (int k0 = 0; k0 < K; k0 += 64) {
    long bko;
    if (BVU) {
      int kk = kbase + k0;
      bko = (long)(kk >> 10) * 2097152 + (kk & 1023);
    } else {
      bko = k0;
    }
    __syncthreads();
#if HAVE_GLL
#pragma unroll
    for (int t = 0; t < 4; ++t) {
      int r = wid * 32 + t * 8;  // uniform slab base row
      gload_lds16(&A[(long)(m0 + r + rl8) * lda + k0 + cg * 8], &As[r * 64]);
      gload_lds16(&B[(long)(n0 + r + rl8) * ldb + bko + cg * 8], &Bs[r * 64]);
    }
#else
#pragma unroll
    for (int it = 0; it < 4; ++it) {
      int idx = tid + it * 256;
      int r = idx >> 3, c = idx & 7;
      int cs = c ^ (r & 7);
      *reinterpret_cast<uint4*>(&As[r * 64 + cs * 8]) =
          *reinterpret_cast<const uint4*>(&A[(long)(m0 + r) * lda + k0 + c * 8]);
      *reinterpret_cast<uint4*>(&Bs[r * 64 + cs * 8]) =
          *reinterpret_cast<const uint4*>(&B[(long)(n0 + r) * ldb + bko + c * 8]);
    }
#endif
    __syncthreads();
#pragma unroll
    for (int ks = 0; ks < 2; ++ks) {
      f16x8 af[4], bfr[4];
      int kc = ks * 4 + rq;
#pragma unroll
      for (int i = 0; i < 4; ++i) {
        int ra = wm + i * 16 + rl;
        af[i] = *reinterpret_cast<const f16x8*>(&As[ra * 64 + ((kc ^ (ra & 7)) << 3)]);
        int rb = wn + i * 16 + rl;
        bfr[i] = *reinterpret_cast<const f16x8*>(&Bs[rb * 64 + ((kc ^ (rb & 7)) << 3)]);
      }
#pragma unroll
      for (int i = 0; i < 4; ++i)
#pragma unroll
        for (int j = 0; j < 4; ++j)
          acc[i][j] = __builtin_amdgcn_mfma_f32_16x16x32_f16(af[i], bfr[j], acc[i][j], 0, 0, 0);
    }
  }

#pragma unroll
  for (int i = 0; i < 4; ++i)
#pragma unroll
    for (int j = 0; j < 4; ++j)
#pragma unroll
      for (int r = 0; r < 4; ++r) {
        int row = m0 + wm + i * 16 + rq * 4 + r;
        int col = n0 + wn + j * 16 + rl;
        float v = acc[i][j][r];
        if (OUT == 1)
          reinterpret_cast<unsigned short*>(Cv)[coff + (long)row * ldc + col] = f2h(v);
        else
          atomicAdd(&reinterpret_cast<float*>(Cv)[coff + (long)row * ldc + col], v);
      }
}

#define DECL_LDS \
  __shared__ unsigned short As[128 * 64]; \
  __shared__ unsigned short Bs[128 * 64];

// L2: weight-fold gemms, grid (8,32), head = XCD c. ONE gemm_core<1,0> call.
// w<16 : Gt_h[b'][a] = sum_d Wq[b', h*512+d] * Wk[a, h*512+d]  (G-fold)
// w>=16: Wvut_h[e][k] = sum_d Wu[h*512+d, e] * Wv[k, h*512+d]  (Wu-fold)
// Identical geometry: lda=ldb=4096, ldc=512, K=512, M=N=512 (4x4 tiles).
__global__ __launch_bounds__(256, 2) void k_gemm_w(
    const unsigned short* __restrict__ Wqf, const unsigned short* __restrict__ Wkf,
    const unsigned short* __restrict__ Wut, const unsigned short* __restrict__ Wvh,
    unsigned short* __restrict__ Gt, unsigned short* __restrict__ Wvut) {
  DECL_LDS
  int c = blockIdx.x, w = blockIdx.y;
  const unsigned short *A, *B;
  unsigned short* C;
  int t;
  if (w < 16) { A = Wqf + c * 512; B = Wkf + c * 512; C = Gt + (long)c * 262144; t = w; }
  else        { A = Wut + c * 512; B = Wvh + c * 512; C = Wvut + (long)c * 262144; t = w - 16; }
  gemm_core<1, 0>(As, Bs, A, B, C, 512, 4096, 4096, 512, 0, (t >> 2) * 128, (t & 3) * 128, 0);
}

// L3: T + VU projections fused, grid (8,256). ONE gemm_core<1,0> call.
// w<128 : T[bt][h*512+b'] = sum_a X[bt,a] * Gt_h[b',a]; head h = c (XCD-pinned
//         where the S-gemm will read it). coff = c*512, ldc 4096.
// w>=128: VUt[h*512+e][b*1024+j] = sum_k Wvut_h[e,k] * X[b*1024+j,k];
//         row-tile head-aligned: m0 = (4c + (w'&3))*128.
__global__ __launch_bounds__(256, 2) void k_gemm_tv(
    const unsigned short* __restrict__ X, const unsigned short* __restrict__ Gt,
    const unsigned short* __restrict__ Wvut, unsigned short* __restrict__ T,
    unsigned short* __restrict__ VUt) {
  DECL_LDS
  int c = blockIdx.x, w = blockIdx.y;
  const unsigned short *A, *B;
  unsigned short* C;
  long coff;
  int m0, n0;
  if (w < 128) {
    A = X; B = Gt + (long)c * 262144; C = T;
    coff = (long)c * 512; m0 = (w >> 2) * 128; n0 = (w & 3) * 128;
  } else {
    int wp = w - 128;
    A = Wvut; B = X; C = VUt;
    coff = 0; m0 = (4 * c + (wp & 3)) * 128; n0 = (wp >> 2) * 128;
  }
  gemm_core<1, 0>(As, Bs, A, B, C, 512, 512, 512, 4096, coff, m0, n0, 0);
}

// L4: S-gemm, grid (8,256). z = c + 8*(w>>6) -> (b,h) pinned to XCD h.
// P[b][i][h*1024+j] = sum_b' T[b*1024+i, h*512+b'] * X[b*1024+j, b'].
__global__ __launch_bounds__(256, 2) void k_gemm_s(
    const unsigned short* __restrict__ X, const unsigned short* __restrict__ T,
    unsigned short* __restrict__ Pb) {
  DECL_LDS
  int c = blockIdx.x, w = blockIdx.y;
  int z = c + 8 * (w >> 6), t = w & 63;
  int b = z >> 3, h = z & 7;
  gemm_core<1, 0>(As, Bs, T + (long)b * 4194304 + h * 512, X + (long)b * 524288, Pb,
                  512, 4096, 512, 8192, (long)b * 8388608 + h * 1024,
                  (t >> 3) * 128, (t & 7) * 128, 0);
}

// O-final: out[b,i,e] += sum_kk Pb[b][i][kk] * VUt[(kk>>10)*512+e][b*1024+(kk&1023)].
// grid (8,64). Group g=(b,kchunk,ihalf): P slab 2 MiB + VU slab 2 MiB = one XCD
// L2; XCD g%8 matches the writers of those k-chunks. atomicAdd (4 adds/elem)
// into d_out pre-zeroed by k_setup z=5.
__global__ __launch_bounds__(256, 2) void k_gemm_out(
    const unsigned short* __restrict__ Pb, const unsigned short* __restrict__ VUt,
    float* __restrict__ out) {
  DECL_LDS
  int c = blockIdx.x, w = blockIdx.y;
  int g = c + 8 * (w >> 4);  // 0..31
  int r = w & 15;
  int b = g >> 3, kc = (g >> 1) & 3, ih = g & 1;
  int y = ih * 4 + (r >> 2);  // 0..7  (i-tile)
  int x = r & 3;              // 0..3  (e-tile)
  gemm_core<2, 1>(As, Bs, Pb + (long)b * 8388608 + kc * 2048, VUt + (long)b * 1024,
                  out, 2048, 8192, 4096, 512, (long)b * 524288, y * 128, x * 128,
                  kc * 2048);
}

// ---------------- softmax: one wave per 1024-chunk, P[b][i][h*1024+j] ----------------
// grid (8,1024): h = blockIdx.x (XCD-aligned with the S-gemm writer).
__global__ __launch_bounds__(256) void k_softmax_x(unsigned short* __restrict__ S) {
  int g = blockIdx.y * 4 + (threadIdx.x >> 6);
  int b = g >> 10, i = g & 1023;
  long base = (long)b * 8388608 + (long)i * 8192 + (long)blockIdx.x * 1024;
  int lane = threadIdx.x & 63;
  f16x8* p = reinterpret_cast<f16x8*>(S + base);
  f16x8 a = p[lane * 2], bb = p[lane * 2 + 1];
  float v[16];
#pragma unroll
  for (int q = 0; q < 8; ++q) { v[q] = (float)a[q]; v[8 + q] = (float)bb[q]; }
  float m = v[0];
#pragma unroll
  for (int q = 1; q < 16; ++q) m = fmaxf(m, v[q]);
#pragma unroll
  for (int o = 32; o; o >>= 1) m = fmaxf(m, __shfl_xor(m, o));
  float s = 0.f;
#pragma unroll
  for (int q = 0; q < 16; ++q) { v[q] = __expf(v[q] - m); s += v[q]; }
#pragma unroll
  for (int o = 32; o; o >>= 1) s += __shfl_xor(s, o);
  float inv = 1.0f / s;
  f16x8 oa, ob;
#pragma unroll
  for (int q = 0; q < 8; ++q) {
    oa[q] = (_Float16)(v[q] * inv);
    ob[q] = (_Float16)(v[8 + q] * inv);
  }
  p[lane * 2] = oa;
  p[lane * 2 + 1] = ob;
}

__global__ void k_sentinel(float* out, float v) { out[0] = v; }

extern "C" void kernel_launch(void* const* d_in, const int* in_sizes, int n_in,
                              void* d_out, int out_size, void* d_ws, size_t ws_size,
                              hipStream_t stream) {
  // setup_inputs dict order: x, Wk, Wq, Wv, Wu
  const float* x  = (const float*)d_in[0];
  const float* Wk = (const float*)d_in[1];
  const float* Wq = (const float*)d_in[2];
  const float* Wv = (const float*)d_in[3];
  const float* Wu = (const float*)d_in[4];
  float* out = (float*)d_out;

  const long SZ_X = 4096L * 512;
  const long SZ_W = 512L * 4096;
  const size_t NEED = 188743680;  // 180 MiB (verified fits; we use 152)

  if (ws_size < NEED) {
    hipMemsetAsync(d_out, 0, (size_t)out_size * 4, stream);
    k_sentinel<<<1, 1, 0, stream>>>(out, (float)ws_size);
    return;
  }

  char* p = (char*)d_ws;
  unsigned short* Xbf  = (unsigned short*)p; p += SZ_X * 2;          //  4 MiB
  unsigned short* Wqf  = (unsigned short*)p; p += SZ_W * 2;          //  4 MiB (in-major)
  unsigned short* Wkf  = (unsigned short*)p; p += SZ_W * 2;          //  4 MiB (in-major)
  unsigned short* Wut  = (unsigned short*)p; p += SZ_W * 2;          //  4 MiB [e][hd]
  unsigned short* Wvut = (unsigned short*)p; p += SZ_W * 2;          //  4 MiB [h][e][k]
  unsigned short* Gt   = (unsigned short*)p; p += 8L * 512 * 512 * 2; // 4 MiB [h][b'][a]
  unsigned short* T    = (unsigned short*)p; p += 4096L * 4096 * 2;  // 32 MiB [bt][h*512+b']
  unsigned short* Pb   = (unsigned short*)p; p += 4096L * 8192 * 2;  // 64 MiB [b][i][h*1024+j]
  unsigned short* VUt  = (unsigned short*)p;                         // 32 MiB [h*512+e][b*1024+j]
  unsigned short* Wvh  = VUt;  // 4 MiB alias: consumed (L2) before VUt written (L3)

  // ---- setup: convert Wq/Wk/x/Wv, transpose Wu, zero d_out (z=5) ----
  k_setup<<<dim3(128, 16, 6), 256, 0, stream>>>(x, Wq, Wk, Wv, Wu, Xbf, Wqf, Wkf, Wvh,
                                                Wut, out);

  // ---- weight folds: Gt_h = Wq_h.Wk_h^T, Wvut_h = Wu_h^T.Wv_h (4.2 GF) ----
  k_gemm_w<<<dim3(8, 32), 256, 0, stream>>>(Wqf, Wkf, Wut, Wvh, Gt, Wvut);

  // ---- T = X.Gt^T (17.2 GF) + VU^T = Wvut.X^T (17.2 GF), fused ----
  k_gemm_tv<<<dim3(8, 256), 256, 0, stream>>>(Xbf, Gt, Wvut, T, VUt);

  // ---- S: P[b][i][h*1024+j] = T.X^T (34.4 GF), B-operand = X (L2-tiny) ----
  k_gemm_s<<<dim3(8, 256), 256, 0, stream>>>(Xbf, T, Pb);

  // ---- softmax over each 1024-chunk of P, in place ----
  k_softmax_x<<<dim3(8, 1024), 256, 0, stream>>>(Pb);

  // ---- out = P . VU^T (strided-head B), L2-sized groups, atomicAdd ----
  k_gemm_out<<<dim3(8, 64), 256, 0, stream>>>(Pb, VUt, out);
}

// Round 12
// 252.274 us; speedup vs baseline: 1.1233x; 1.0435x over previous
//
#include <hip/hip_runtime.h>
#include <stdint.h>

typedef _Float16 f16x8 __attribute__((ext_vector_type(8)));
typedef float f32x4 __attribute__((ext_vector_type(4)));

__device__ __forceinline__ unsigned short f2h(float f) {
  _Float16 h = (_Float16)f;
  return __builtin_bit_cast(unsigned short, h);
}

#if __has_builtin(__builtin_amdgcn_global_load_lds)
#define HAVE_GLL 1
__device__ __forceinline__ void gload_lds16(const void* g, void* l) {
  auto gp = reinterpret_cast<const __attribute__((address_space(1))) void*>(
      reinterpret_cast<uintptr_t>(g));
  auto lp = reinterpret_cast<__attribute__((address_space(3))) void*>(
      reinterpret_cast<uintptr_t>(l));
  __builtin_amdgcn_global_load_lds(gp, lp, 16, 0, 0);
}
#else
#define HAVE_GLL 0
#endif

// ---------------- fused setup ----------------
__device__ __forceinline__ void transpose_core(const float* in, unsigned short* out,
                                               int R, int C, int c0, int r0) {
  __shared__ float t[32][33];
  int tx = threadIdx.x & 31, ty = threadIdx.x >> 5;  // 32 x 8
#pragma unroll
  for (int i = 0; i < 32; i += 8)
    t[ty + i][tx] = in[(long)(r0 + ty + i) * C + (c0 + tx)];
  __syncthreads();
#pragma unroll
  for (int i = 0; i < 32; i += 8)
    out[(long)(c0 + ty + i) * R + (r0 + tx)] = f2h(t[tx][ty + i]);
}

// grid (128,16,5): z=0 convert Wq (in-major: G-fold consumes it directly),
// z=1 convert Wk, z=2 transpose Wu [4096,512]->[512,4096], z=3 convert x,
// z=4 convert Wv.
__global__ __launch_bounds__(256) void k_setup(
    const float* __restrict__ x, const float* __restrict__ Wq, const float* __restrict__ Wk,
    const float* __restrict__ Wv, const float* __restrict__ Wu,
    unsigned short* __restrict__ Xh, unsigned short* __restrict__ Wqf,
    unsigned short* __restrict__ Wkf, unsigned short* __restrict__ Wvh,
    unsigned short* __restrict__ Wut) {
  int z = blockIdx.z;
  if (z == 2) {
    transpose_core(Wu, Wut, 4096, 512, blockIdx.y * 32, blockIdx.x * 32);
  } else {
    const float* in = (z == 0) ? Wq : (z == 1) ? Wk : (z == 3) ? x : Wv;
    unsigned short* o = (z == 0) ? Wqf : (z == 1) ? Wkf : (z == 3) ? Xh : Wvh;
    int i = (blockIdx.y * 128 + blockIdx.x) * 256 + threadIdx.x;
    float4 v = reinterpret_cast<const float4*>(in)[i];
    ushort4 u;
    u.x = f2h(v.x); u.y = f2h(v.y); u.z = f2h(v.z); u.w = f2h(v.w);
    reinterpret_cast<ushort4*>(o)[i] = u;
  }
}

// ---------------- GEMM core: C[M,N] = A[M,K] * B[N,K]^T ----------------
// 128x128 tile, BK=64, 256 threads (4 waves, 2x2 of 64x64), mfma 16x16x32 f16.
// LDS XOR-swizzled at 16B granularity; staging via global_load_lds(16B).
// LDS passed in. ONE template instantiation per kernel, selection only via
// pointer/geometry args (dual instantiation inflated VGPR 64->88, -15%: R8/R9).
// OUT: 0 fp32 store, 1 fp16 store.  (atomicAdd path removed: R11 showed every
// cross-XCD fp32 atomic is a serialized HBM RMW — 4x write amplification.)
// BVU: B rows live in VUt[h*512+e][b*1024+j]; staging addr uses global k
// kk = kbase+k0: e*ldb + (kk>>10)*2097152 + (kk&1023).
template <int OUT, int BVU>
__device__ __forceinline__ void gemm_core(unsigned short* __restrict__ As,
                                          unsigned short* __restrict__ Bs,
                                          const unsigned short* __restrict__ A,
                                          const unsigned short* __restrict__ B,
                                          void* __restrict__ Cv, int K, int lda, int ldb,
                                          int ldc, long coff, int m0, int n0, int kbase) {
  int tid = threadIdx.x;
  int wid = tid >> 6, lane = tid & 63;
  int wm = (wid >> 1) * 64, wn = (wid & 1) * 64;
  int rq = lane >> 4, rl = lane & 15;

  f32x4 acc[4][4];
#pragma unroll
  for (int i = 0; i < 4; ++i)
#pragma unroll
    for (int j = 0; j < 4; ++j) acc[i][j] = (f32x4){0.f, 0.f, 0.f, 0.f};

#if HAVE_GLL
  int cg = (lane & 7) ^ ((lane >> 3) & 7);  // permuted global chunk -> swizzled LDS
  int rl8 = lane >> 3;                      // row within 8-row group
#endif

  for (int k0 = 0; k0 < K; k0 += 64) {
    long bko;
    if (BVU) {
      int kk = kbase + k0;
      bko = (long)(kk >> 10) * 2097152 + (kk & 1023);
    } else {
      bko = k0;
    }
    __syncthreads();
#if HAVE_GLL
#pragma unroll
    for (int t = 0; t < 4; ++t) {
      int r = wid * 32 + t * 8;  // uniform slab base row
      gload_lds16(&A[(long)(m0 + r + rl8) * lda + k0 + cg * 8], &As[r * 64]);
      gload_lds16(&B[(long)(n0 + r + rl8) * ldb + bko + cg * 8], &Bs[r * 64]);
    }
#else
#pragma unroll
    for (int it = 0; it < 4; ++it) {
      int idx = tid + it * 256;
      int r = idx >> 3, c = idx & 7;
      int cs = c ^ (r & 7);
      *reinterpret_cast<uint4*>(&As[r * 64 + cs * 8]) =
          *reinterpret_cast<const uint4*>(&A[(long)(m0 + r) * lda + k0 + c * 8]);
      *reinterpret_cast<uint4*>(&Bs[r * 64 + cs * 8]) =
          *reinterpret_cast<const uint4*>(&B[(long)(n0 + r) * ldb + bko + c * 8]);
    }
#endif
    __syncthreads();
#pragma unroll
    for (int ks = 0; ks < 2; ++ks) {
      f16x8 af[4], bfr[4];
      int kc = ks * 4 + rq;
#pragma unroll
      for (int i = 0; i < 4; ++i) {
        int ra = wm + i * 16 + rl;
        af[i] = *reinterpret_cast<const f16x8*>(&As[ra * 64 + ((kc ^ (ra & 7)) << 3)]);
        int rb = wn + i * 16 + rl;
        bfr[i] = *reinterpret_cast<const f16x8*>(&Bs[rb * 64 + ((kc ^ (rb & 7)) << 3)]);
      }
#pragma unroll
      for (int i = 0; i < 4; ++i)
#pragma unroll
        for (int j = 0; j < 4; ++j)
          acc[i][j] = __builtin_amdgcn_mfma_f32_16x16x32_f16(af[i], bfr[j], acc[i][j], 0, 0, 0);
    }
  }

#pragma unroll
  for (int i = 0; i < 4; ++i)
#pragma unroll
    for (int j = 0; j < 4; ++j)
#pragma unroll
      for (int r = 0; r < 4; ++r) {
        int row = m0 + wm + i * 16 + rq * 4 + r;
        int col = n0 + wn + j * 16 + rl;
        float v = acc[i][j][r];
        if (OUT == 1)
          reinterpret_cast<unsigned short*>(Cv)[coff + (long)row * ldc + col] = f2h(v);
        else
          reinterpret_cast<float*>(Cv)[coff + (long)row * ldc + col] = v;
      }
}

#define DECL_LDS \
  __shared__ unsigned short As[128 * 64]; \
  __shared__ unsigned short Bs[128 * 64];

// L2: weight-fold gemms, grid (8,32), head = XCD c. ONE gemm_core<1,0> call.
// w<16 : Gt_h[b'][a] = sum_d Wq[b', h*512+d] * Wk[a, h*512+d]  (G-fold)
// w>=16: Wvut_h[e][k] = sum_d Wu[h*512+d, e] * Wv[k, h*512+d]  (Wu-fold)
__global__ __launch_bounds__(256, 2) void k_gemm_w(
    const unsigned short* __restrict__ Wqf, const unsigned short* __restrict__ Wkf,
    const unsigned short* __restrict__ Wut, const unsigned short* __restrict__ Wvh,
    unsigned short* __restrict__ Gt, unsigned short* __restrict__ Wvut) {
  DECL_LDS
  int c = blockIdx.x, w = blockIdx.y;
  const unsigned short *A, *B;
  unsigned short* C;
  int t;
  if (w < 16) { A = Wqf + c * 512; B = Wkf + c * 512; C = Gt + (long)c * 262144; t = w; }
  else        { A = Wut + c * 512; B = Wvh + c * 512; C = Wvut + (long)c * 262144; t = w - 16; }
  gemm_core<1, 0>(As, Bs, A, B, C, 512, 4096, 4096, 512, 0, (t >> 2) * 128, (t & 3) * 128, 0);
}

// L3: T + VU projections fused, grid (8,256). ONE gemm_core<1,0> call.
// w<128 : T[bt][h*512+b'] = sum_a X[bt,a] * Gt_h[b',a]; h = c (XCD-pinned).
// w>=128: VUt[h*512+e][b*1024+j] = sum_k Wvut_h[e,k] * X[b*1024+j,k].
__global__ __launch_bounds__(256, 2) void k_gemm_tv(
    const unsigned short* __restrict__ X, const unsigned short* __restrict__ Gt,
    const unsigned short* __restrict__ Wvut, unsigned short* __restrict__ T,
    unsigned short* __restrict__ VUt) {
  DECL_LDS
  int c = blockIdx.x, w = blockIdx.y;
  const unsigned short *A, *B;
  unsigned short* C;
  long coff;
  int m0, n0;
  if (w < 128) {
    A = X; B = Gt + (long)c * 262144; C = T;
    coff = (long)c * 512; m0 = (w >> 2) * 128; n0 = (w & 3) * 128;
  } else {
    int wp = w - 128;
    A = Wvut; B = X; C = VUt;
    coff = 0; m0 = (4 * c + (wp & 3)) * 128; n0 = (wp >> 2) * 128;
  }
  gemm_core<1, 0>(As, Bs, A, B, C, 512, 512, 512, 4096, coff, m0, n0, 0);
}

// L4: S-gemm, grid (8,256). z = c + 8*(w>>6) -> (b,h) pinned to XCD h.
// P[b][i][h*1024+j] = sum_b' T[b*1024+i, h*512+b'] * X[b*1024+j, b'].
__global__ __launch_bounds__(256, 2) void k_gemm_s(
    const unsigned short* __restrict__ X, const unsigned short* __restrict__ T,
    unsigned short* __restrict__ Pb) {
  DECL_LDS
  int c = blockIdx.x, w = blockIdx.y;
  int z = c + 8 * (w >> 6), t = w & 63;
  int b = z >> 3, h = z & 7;
  gemm_core<1, 0>(As, Bs, T + (long)b * 4194304 + h * 512, X + (long)b * 524288, Pb,
                  512, 4096, 512, 8192, (long)b * 8388608 + h * 1024,
                  (t >> 3) * 128, (t & 7) * 128, 0);
}

// O-final: Opart[kc][b*1024+i][e] = sum_{kk in chunk} Pb[b][i][kk] *
// VUt[(kk>>10)*512+e][b*1024+(kk&1023)]. grid (8,64), plain fp32 stores (no
// atomics). Group g=(b,kchunk,ihalf): P slab 2 MiB + VU slab 2 MiB = one XCD L2.
__global__ __launch_bounds__(256, 2) void k_gemm_out(
    const unsigned short* __restrict__ Pb, const unsigned short* __restrict__ VUt,
    float* __restrict__ Opart) {
  DECL_LDS
  int c = blockIdx.x, w = blockIdx.y;
  int g = c + 8 * (w >> 4);  // 0..31
  int r = w & 15;
  int b = g >> 3, kc = (g >> 1) & 3, ih = g & 1;
  int y = ih * 4 + (r >> 2);  // 0..7  (i-tile)
  int x = r & 3;              // 0..3  (e-tile)
  gemm_core<0, 1>(As, Bs, Pb + (long)b * 8388608 + kc * 2048, VUt + (long)b * 1024,
                  Opart, 2048, 8192, 4096, 512,
                  (long)kc * 2097152 + (long)b * 524288, y * 128, x * 128, kc * 2048);
}

// reduce: out[i] = sum_kc Opart[kc][i]. 2M floats, float4 per thread.
__global__ __launch_bounds__(256) void k_reduce(const float* __restrict__ Opart,
                                                float* __restrict__ out) {
  int i = blockIdx.x * 256 + threadIdx.x;
  float4 a = reinterpret_cast<const float4*>(Opart)[i];
  float4 b = reinterpret_cast<const float4*>(Opart + 2097152)[i];
  float4 c = reinterpret_cast<const float4*>(Opart + 4194304)[i];
  float4 d = reinterpret_cast<const float4*>(Opart + 6291456)[i];
  float4 o;
  o.x = (a.x + b.x) + (c.x + d.x);
  o.y = (a.y + b.y) + (c.y + d.y);
  o.z = (a.z + b.z) + (c.z + d.z);
  o.w = (a.w + b.w) + (c.w + d.w);
  reinterpret_cast<float4*>(out)[i] = o;
}

// ---------------- softmax: one wave per 1024-chunk, P[b][i][h*1024+j] ----------------
// grid (8,1024): h = blockIdx.x (XCD-aligned with the S-gemm writer).
__global__ __launch_bounds__(256) void k_softmax_x(unsigned short* __restrict__ S) {
  int g = blockIdx.y * 4 + (threadIdx.x >> 6);
  int b = g >> 10, i = g & 1023;
  long base = (long)b * 8388608 + (long)i * 8192 + (long)blockIdx.x * 1024;
  int lane = threadIdx.x & 63;
  f16x8* p = reinterpret_cast<f16x8*>(S + base);
  f16x8 a = p[lane * 2], bb = p[lane * 2 + 1];
  float v[16];
#pragma unroll
  for (int q = 0; q < 8; ++q) { v[q] = (float)a[q]; v[8 + q] = (float)bb[q]; }
  float m = v[0];
#pragma unroll
  for (int q = 1; q < 16; ++q) m = fmaxf(m, v[q]);
#pragma unroll
  for (int o = 32; o; o >>= 1) m = fmaxf(m, __shfl_xor(m, o));
  float s = 0.f;
#pragma unroll
  for (int q = 0; q < 16; ++q) { v[q] = __expf(v[q] - m); s += v[q]; }
#pragma unroll
  for (int o = 32; o; o >>= 1) s += __shfl_xor(s, o);
  float inv = 1.0f / s;
  f16x8 oa, ob;
#pragma unroll
  for (int q = 0; q < 8; ++q) {
    oa[q] = (_Float16)(v[q] * inv);
    ob[q] = (_Float16)(v[8 + q] * inv);
  }
  p[lane * 2] = oa;
  p[lane * 2 + 1] = ob;
}

__global__ void k_sentinel(float* out, float v) { out[0] = v; }

extern "C" void kernel_launch(void* const* d_in, const int* in_sizes, int n_in,
                              void* d_out, int out_size, void* d_ws, size_t ws_size,
                              hipStream_t stream) {
  // setup_inputs dict order: x, Wk, Wq, Wv, Wu
  const float* x  = (const float*)d_in[0];
  const float* Wk = (const float*)d_in[1];
  const float* Wq = (const float*)d_in[2];
  const float* Wv = (const float*)d_in[3];
  const float* Wu = (const float*)d_in[4];
  float* out = (float*)d_out;

  const long SZ_X = 4096L * 512;
  const long SZ_W = 512L * 4096;
  const size_t NEED = 188743680;  // 180 MiB (verified fits; we use 152)

  if (ws_size < NEED) {
    hipMemsetAsync(d_out, 0, (size_t)out_size * 4, stream);
    k_sentinel<<<1, 1, 0, stream>>>(out, (float)ws_size);
    return;
  }

  char* p = (char*)d_ws;
  unsigned short* Xbf  = (unsigned short*)p; p += SZ_X * 2;          //  4 MiB
  unsigned short* Wqf  = (unsigned short*)p; p += SZ_W * 2;          //  4 MiB (in-major)
  unsigned short* Wkf  = (unsigned short*)p; p += SZ_W * 2;          //  4 MiB (in-major)
  unsigned short* Wut  = (unsigned short*)p; p += SZ_W * 2;          //  4 MiB [e][hd]
  unsigned short* Wvut = (unsigned short*)p; p += SZ_W * 2;          //  4 MiB [h][e][k]
  unsigned short* Gt   = (unsigned short*)p; p += 8L * 512 * 512 * 2; // 4 MiB [h][b'][a]
  unsigned short* T    = (unsigned short*)p; p += 4096L * 4096 * 2;  // 32 MiB [bt][h*512+b']
  unsigned short* Pb   = (unsigned short*)p; p += 4096L * 8192 * 2;  // 64 MiB [b][i][h*1024+j]
  unsigned short* VUt  = (unsigned short*)p;                         // 32 MiB [h*512+e][b*1024+j]
  unsigned short* Wvh  = VUt;       // 4 MiB alias: consumed (L2) before VUt written (L3)
  float* Opart = (float*)T;         // 32 MiB alias: T dead after S-gemm; 4x[4096][512] fp32

  // ---- setup: convert Wq/Wk/x/Wv, transpose Wu ----
  k_setup<<<dim3(128, 16, 5), 256, 0, stream>>>(x, Wq, Wk, Wv, Wu, Xbf, Wqf, Wkf, Wvh, Wut);

  // ---- weight folds: Gt_h = Wq_h.Wk_h^T, Wvut_h = Wu_h^T.Wv_h (4.2 GF) ----
  k_gemm_w<<<dim3(8, 32), 256, 0, stream>>>(Wqf, Wkf, Wut, Wvh, Gt, Wvut);

  // ---- T = X.Gt^T (17.2 GF) + VU^T = Wvut.X^T (17.2 GF), fused ----
  k_gemm_tv<<<dim3(8, 256), 256, 0, stream>>>(Xbf, Gt, Wvut, T, VUt);

  // ---- S: P[b][i][h*1024+j] = T.X^T (34.4 GF), B-operand = X (L2-tiny) ----
  k_gemm_s<<<dim3(8, 256), 256, 0, stream>>>(Xbf, T, Pb);

  // ---- softmax over each 1024-chunk of P, in place ----
  k_softmax_x<<<dim3(8, 1024), 256, 0, stream>>>(Pb);

  // ---- out partials = P . VU^T (strided-head B), plain fp32 stores ----
  k_gemm_out<<<dim3(8, 64), 256, 0, stream>>>(Pb, VUt, Opart);

  // ---- out = sum of 4 partials ----
  k_reduce<<<2048, 256, 0, stream>>>(Opart, out);
}

// Round 13
// 234.914 us; speedup vs baseline: 1.2063x; 1.0739x over previous
//
#include <hip/hip_runtime.h>
#include <stdint.h>

typedef _Float16 f16x8 __attribute__((ext_vector_type(8)));
typedef float f32x4 __attribute__((ext_vector_type(4)));

__device__ __forceinline__ unsigned short f2h(float f) {
  _Float16 h = (_Float16)f;
  return __builtin_bit_cast(unsigned short, h);
}

#if __has_builtin(__builtin_amdgcn_global_load_lds)
#define HAVE_GLL 1
__device__ __forceinline__ void gload_lds16(const void* g, void* l) {
  auto gp = reinterpret_cast<const __attribute__((address_space(1))) void*>(
      reinterpret_cast<uintptr_t>(g));
  auto lp = reinterpret_cast<__attribute__((address_space(3))) void*>(
      reinterpret_cast<uintptr_t>(l));
  __builtin_amdgcn_global_load_lds(gp, lp, 16, 0, 0);
}
#else
#define HAVE_GLL 0
#endif

// ---------------- GEMM core: C[M,N] = A[M,K] * B[N,K]^T (fp16 inputs) ----------------
// 128x128 tile, BK=64, 256 threads (4 waves, 2x2 of 64x64), mfma 16x16x32 f16.
// LDS XOR-swizzled at 16B granularity; staging via global_load_lds(16B).
// LDS passed in. ONE template instantiation per kernel, selection only via
// pointer/geometry args (dual instantiation inflated VGPR 64->88, -15%: R8/R9).
// OUT: 0 fp32 store, 1 fp16 store.  (atomicAdd removed: R11 showed cross-XCD
// fp32 atomics are serialized HBM RMW — 4x write amplification.)
// BVU: B rows live in VUt[h*512+e][b*1024+j]; staging addr uses global k
// kk = kbase+k0: e*ldb + (kk>>10)*2097152 + (kk&1023).
template <int OUT, int BVU>
__device__ __forceinline__ void gemm_core(unsigned short* __restrict__ As,
                                          unsigned short* __restrict__ Bs,
                                          const unsigned short* __restrict__ A,
                                          const unsigned short* __restrict__ B,
                                          void* __restrict__ Cv, int K, int lda, int ldb,
                                          int ldc, long coff, int m0, int n0, int kbase) {
  int tid = threadIdx.x;
  int wid = tid >> 6, lane = tid & 63;
  int wm = (wid >> 1) * 64, wn = (wid & 1) * 64;
  int rq = lane >> 4, rl = lane & 15;

  f32x4 acc[4][4];
#pragma unroll
  for (int i = 0; i < 4; ++i)
#pragma unroll
    for (int j = 0; j < 4; ++j) acc[i][j] = (f32x4){0.f, 0.f, 0.f, 0.f};

#if HAVE_GLL
  int cg = (lane & 7) ^ ((lane >> 3) & 7);  // permuted global chunk -> swizzled LDS
  int rl8 = lane >> 3;                      // row within 8-row group
#endif

  for (int k0 = 0; k0 < K; k0 += 64) {
    long bko;
    if (BVU) {
      int kk = kbase + k0;
      bko = (long)(kk >> 10) * 2097152 + (kk & 1023);
    } else {
      bko = k0;
    }
    __syncthreads();
#if HAVE_GLL
#pragma unroll
    for (int t = 0; t < 4; ++t) {
      int r = wid * 32 + t * 8;  // uniform slab base row
      gload_lds16(&A[(long)(m0 + r + rl8) * lda + k0 + cg * 8], &As[r * 64]);
      gload_lds16(&B[(long)(n0 + r + rl8) * ldb + bko + cg * 8], &Bs[r * 64]);
    }
#else
#pragma unroll
    for (int it = 0; it < 4; ++it) {
      int idx = tid + it * 256;
      int r = idx >> 3, c = idx & 7;
      int cs = c ^ (r & 7);
      *reinterpret_cast<uint4*>(&As[r * 64 + cs * 8]) =
          *reinterpret_cast<const uint4*>(&A[(long)(m0 + r) * lda + k0 + c * 8]);
      *reinterpret_cast<uint4*>(&Bs[r * 64 + cs * 8]) =
          *reinterpret_cast<const uint4*>(&B[(long)(n0 + r) * ldb + bko + c * 8]);
    }
#endif
    __syncthreads();
#pragma unroll
    for (int ks = 0; ks < 2; ++ks) {
      f16x8 af[4], bfr[4];
      int kc = ks * 4 + rq;
#pragma unroll
      for (int i = 0; i < 4; ++i) {
        int ra = wm + i * 16 + rl;
        af[i] = *reinterpret_cast<const f16x8*>(&As[ra * 64 + ((kc ^ (ra & 7)) << 3)]);
        int rb = wn + i * 16 + rl;
        bfr[i] = *reinterpret_cast<const f16x8*>(&Bs[rb * 64 + ((kc ^ (rb & 7)) << 3)]);
      }
#pragma unroll
      for (int i = 0; i < 4; ++i)
#pragma unroll
        for (int j = 0; j < 4; ++j)
          acc[i][j] = __builtin_amdgcn_mfma_f32_16x16x32_f16(af[i], bfr[j], acc[i][j], 0, 0, 0);
    }
  }

#pragma unroll
  for (int i = 0; i < 4; ++i)
#pragma unroll
    for (int j = 0; j < 4; ++j)
#pragma unroll
      for (int r = 0; r < 4; ++r) {
        int row = m0 + wm + i * 16 + rq * 4 + r;
        int col = n0 + wn + j * 16 + rl;
        float v = acc[i][j][r];
        if (OUT == 1)
          reinterpret_cast<unsigned short*>(Cv)[coff + (long)row * ldc + col] = f2h(v);
        else
          reinterpret_cast<float*>(Cv)[coff + (long)row * ldc + col] = v;
      }
}

// ---------------- w_core: same 128x128xBK64 gemm but staging from RAW fp32 ----------------
// Converts f32->f16 in registers during staging (same RTN rounding the old setup
// kernel used), writing the same XOR-swizzled LDS layout. atrans (wave-uniform):
// A element (m,k) at A32[(k0+k)*512 + m0+m] (the Wu transposed read). Only the
// tiny weight-fold launch uses this core — 48 gemm blocks, perf non-critical.
__device__ __forceinline__ void w_core(unsigned short* __restrict__ As,
                                       unsigned short* __restrict__ Bs,
                                       const float* __restrict__ A32,
                                       const float* __restrict__ B32,
                                       unsigned short* __restrict__ C,
                                       int lda, int ldb, bool atrans, int m0, int n0) {
  int tid = threadIdx.x;
  int wid = tid >> 6, lane = tid & 63;
  int wm = (wid >> 1) * 64, wn = (wid & 1) * 64;
  int rq = lane >> 4, rl = lane & 15;

  f32x4 acc[4][4];
#pragma unroll
  for (int i = 0; i < 4; ++i)
#pragma unroll
    for (int j = 0; j < 4; ++j) acc[i][j] = (f32x4){0.f, 0.f, 0.f, 0.f};

  for (int k0 = 0; k0 < 512; k0 += 64) {
    __syncthreads();
    if (!atrans) {
#pragma unroll
      for (int it = 0; it < 8; ++it) {
        int idx = it * 256 + tid;
        int r = idx >> 4, kq = idx & 15;
        float4 v = *reinterpret_cast<const float4*>(&A32[(long)(m0 + r) * lda + k0 + kq * 4]);
        ushort4 u;
        u.x = f2h(v.x); u.y = f2h(v.y); u.z = f2h(v.z); u.w = f2h(v.w);
        int cs = (kq >> 1) ^ (r & 7);
        *reinterpret_cast<ushort4*>(&As[r * 64 + cs * 8 + (kq & 1) * 4]) = u;
      }
    } else {
#pragma unroll
      for (int it = 0; it < 32; ++it) {
        int idx = it * 256 + tid;
        int m = idx & 127, d = idx >> 7;  // coalesced over m (128x4B runs)
        float v = A32[(long)(k0 + d) * 512 + m0 + m];
        int cs = (d >> 3) ^ (m & 7);
        As[m * 64 + cs * 8 + (d & 7)] = f2h(v);
      }
    }
#pragma unroll
    for (int it = 0; it < 8; ++it) {
      int idx = it * 256 + tid;
      int r = idx >> 4, kq = idx & 15;
      float4 v = *reinterpret_cast<const float4*>(&B32[(long)(n0 + r) * ldb + k0 + kq * 4]);
      ushort4 u;
      u.x = f2h(v.x); u.y = f2h(v.y); u.z = f2h(v.z); u.w = f2h(v.w);
      int cs = (kq >> 1) ^ (r & 7);
      *reinterpret_cast<ushort4*>(&Bs[r * 64 + cs * 8 + (kq & 1) * 4]) = u;
    }
    __syncthreads();
#pragma unroll
    for (int ks = 0; ks < 2; ++ks) {
      f16x8 af[4], bfr[4];
      int kc = ks * 4 + rq;
#pragma unroll
      for (int i = 0; i < 4; ++i) {
        int ra = wm + i * 16 + rl;
        af[i] = *reinterpret_cast<const f16x8*>(&As[ra * 64 + ((kc ^ (ra & 7)) << 3)]);
        int rb = wn + i * 16 + rl;
        bfr[i] = *reinterpret_cast<const f16x8*>(&Bs[rb * 64 + ((kc ^ (rb & 7)) << 3)]);
      }
#pragma unroll
      for (int i = 0; i < 4; ++i)
#pragma unroll
        for (int j = 0; j < 4; ++j)
          acc[i][j] = __builtin_amdgcn_mfma_f32_16x16x32_f16(af[i], bfr[j], acc[i][j], 0, 0, 0);
    }
  }

#pragma unroll
  for (int i = 0; i < 4; ++i)
#pragma unroll
    for (int j = 0; j < 4; ++j)
#pragma unroll
      for (int r = 0; r < 4; ++r) {
        int row = m0 + wm + i * 16 + rq * 4 + r;
        int col = n0 + wn + j * 16 + rl;
        C[(long)row * 512 + col] = f2h(acc[i][j][r]);
      }
}

#define DECL_LDS \
  __shared__ unsigned short As[128 * 64]; \
  __shared__ unsigned short Bs[128 * 64];

// L1 (setup+folds merged, 7->6 nodes): grid (8, 288).
// w>=32: convert x fp32->fp16, block bi=(w-32)*8+c of 2048 (independent work).
// w<16 : Gt_h[b'][a] = sum_d Wq[b', h*512+d]*Wk[a, h*512+d], h=c, fp32-staged.
// w in [16,32): Wvut_h[e][k] = sum_d Wu[h*512+d, e]*Wv[k, h*512+d], A transposed.
__global__ __launch_bounds__(256, 2) void k_wsetup(
    const float* __restrict__ x, const float* __restrict__ Wq, const float* __restrict__ Wk,
    const float* __restrict__ Wv, const float* __restrict__ Wu,
    unsigned short* __restrict__ Xh, unsigned short* __restrict__ Gt,
    unsigned short* __restrict__ Wvut) {
  DECL_LDS
  int c = blockIdx.x, w = blockIdx.y;
  if (w >= 32) {
    int i = ((w - 32) * 8 + c) * 256 + threadIdx.x;
    float4 v = reinterpret_cast<const float4*>(x)[i];
    ushort4 u;
    u.x = f2h(v.x); u.y = f2h(v.y); u.z = f2h(v.z); u.w = f2h(v.w);
    reinterpret_cast<ushort4*>(Xh)[i] = u;
    return;
  }
  const float *A32, *B32;
  unsigned short* C;
  int lda;
  bool atrans;
  int t;
  if (w < 16) {
    A32 = Wq + c * 512; B32 = Wk + c * 512; C = Gt + (long)c * 262144;
    lda = 4096; atrans = false; t = w;
  } else {
    A32 = Wu + (long)c * 262144; B32 = Wv + c * 512; C = Wvut + (long)c * 262144;
    lda = 512; atrans = true; t = w - 16;
  }
  w_core(As, Bs, A32, B32, C, lda, 4096, atrans, (t >> 2) * 128, (t & 3) * 128);
}

// L2: T + VU projections fused, grid (8,256). ONE gemm_core<1,0> call.
// w<128 : T[bt][h*512+b'] = sum_a X[bt,a] * Gt_h[b',a]; h = c (XCD-pinned).
// w>=128: VUt[h*512+e][b*1024+j] = sum_k Wvut_h[e,k] * X[b*1024+j,k].
__global__ __launch_bounds__(256, 2) void k_gemm_tv(
    const unsigned short* __restrict__ X, const unsigned short* __restrict__ Gt,
    const unsigned short* __restrict__ Wvut, unsigned short* __restrict__ T,
    unsigned short* __restrict__ VUt) {
  DECL_LDS
  int c = blockIdx.x, w = blockIdx.y;
  const unsigned short *A, *B;
  unsigned short* C;
  long coff;
  int m0, n0;
  if (w < 128) {
    A = X; B = Gt + (long)c * 262144; C = T;
    coff = (long)c * 512; m0 = (w >> 2) * 128; n0 = (w & 3) * 128;
  } else {
    int wp = w - 128;
    A = Wvut; B = X; C = VUt;
    coff = 0; m0 = (4 * c + (wp & 3)) * 128; n0 = (wp >> 2) * 128;
  }
  gemm_core<1, 0>(As, Bs, A, B, C, 512, 512, 512, 4096, coff, m0, n0, 0);
}

// L3: S-gemm, grid (8,256). z = c + 8*(w>>6) -> (b,h) pinned to XCD h.
// P[b][i][h*1024+j] = sum_b' T[b*1024+i, h*512+b'] * X[b*1024+j, b'].
__global__ __launch_bounds__(256, 2) void k_gemm_s(
    const unsigned short* __restrict__ X, const unsigned short* __restrict__ T,
    unsigned short* __restrict__ Pb) {
  DECL_LDS
  int c = blockIdx.x, w = blockIdx.y;
  int z = c + 8 * (w >> 6), t = w & 63;
  int b = z >> 3, h = z & 7;
  gemm_core<1, 0>(As, Bs, T + (long)b * 4194304 + h * 512, X + (long)b * 524288, Pb,
                  512, 4096, 512, 8192, (long)b * 8388608 + h * 1024,
                  (t >> 3) * 128, (t & 7) * 128, 0);
}

// L5: O-partials: Opart[kc][b*1024+i][e] = sum_{kk in chunk} Pb[b][i][kk] *
// VUt[(kk>>10)*512+e][b*1024+(kk&1023)]. grid (8,64), plain fp32 stores.
// Group g=(b,kchunk,ihalf): P slab 2 MiB + VU slab 2 MiB = one XCD L2.
__global__ __launch_bounds__(256, 2) void k_gemm_out(
    const unsigned short* __restrict__ Pb, const unsigned short* __restrict__ VUt,
    float* __restrict__ Opart) {
  DECL_LDS
  int c = blockIdx.x, w = blockIdx.y;
  int g = c + 8 * (w >> 4);  // 0..31
  int r = w & 15;
  int b = g >> 3, kc = (g >> 1) & 3, ih = g & 1;
  int y = ih * 4 + (r >> 2);  // 0..7  (i-tile)
  int x = r & 3;              // 0..3  (e-tile)
  gemm_core<0, 1>(As, Bs, Pb + (long)b * 8388608 + kc * 2048, VUt + (long)b * 1024,
                  Opart, 2048, 8192, 4096, 512,
                  (long)kc * 2097152 + (long)b * 524288, y * 128, x * 128, kc * 2048);
}

// L6: out[i] = sum_kc Opart[kc][i]. 2M floats, float4 per thread.
__global__ __launch_bounds__(256) void k_reduce(const float* __restrict__ Opart,
                                                float* __restrict__ out) {
  int i = blockIdx.x * 256 + threadIdx.x;
  float4 a = reinterpret_cast<const float4*>(Opart)[i];
  float4 b = reinterpret_cast<const float4*>(Opart + 2097152)[i];
  float4 c = reinterpret_cast<const float4*>(Opart + 4194304)[i];
  float4 d = reinterpret_cast<const float4*>(Opart + 6291456)[i];
  float4 o;
  o.x = (a.x + b.x) + (c.x + d.x);
  o.y = (a.y + b.y) + (c.y + d.y);
  o.z = (a.z + b.z) + (c.z + d.z);
  o.w = (a.w + b.w) + (c.w + d.w);
  reinterpret_cast<float4*>(out)[i] = o;
}

// L4: softmax, one wave per 1024-chunk of P[b][i][h*1024+j], in place.
// grid (8,1024): h = blockIdx.x (XCD-aligned with the S-gemm writer).
__global__ __launch_bounds__(256) void k_softmax_x(unsigned short* __restrict__ S) {
  int g = blockIdx.y * 4 + (threadIdx.x >> 6);
  int b = g >> 10, i = g & 1023;
  long base = (long)b * 8388608 + (long)i * 8192 + (long)blockIdx.x * 1024;
  int lane = threadIdx.x & 63;
  f16x8* p = reinterpret_cast<f16x8*>(S + base);
  f16x8 a = p[lane * 2], bb = p[lane * 2 + 1];
  float v[16];
#pragma unroll
  for (int q = 0; q < 8; ++q) { v[q] = (float)a[q]; v[8 + q] = (float)bb[q]; }
  float m = v[0];
#pragma unroll
  for (int q = 1; q < 16; ++q) m = fmaxf(m, v[q]);
#pragma unroll
  for (int o = 32; o; o >>= 1) m = fmaxf(m, __shfl_xor(m, o));
  float s = 0.f;
#pragma unroll
  for (int q = 0; q < 16; ++q) { v[q] = __expf(v[q] - m); s += v[q]; }
#pragma unroll
  for (int o = 32; o; o >>= 1) s += __shfl_xor(s, o);
  float inv = 1.0f / s;
  f16x8 oa, ob;
#pragma unroll
  for (int q = 0; q < 8; ++q) {
    oa[q] = (_Float16)(v[q] * inv);
    ob[q] = (_Float16)(v[8 + q] * inv);
  }
  p[lane * 2] = oa;
  p[lane * 2 + 1] = ob;
}

__global__ void k_sentinel(float* out, float v) { out[0] = v; }

extern "C" void kernel_launch(void* const* d_in, const int* in_sizes, int n_in,
                              void* d_out, int out_size, void* d_ws, size_t ws_size,
                              hipStream_t stream) {
  // setup_inputs dict order: x, Wk, Wq, Wv, Wu
  const float* x  = (const float*)d_in[0];
  const float* Wk = (const float*)d_in[1];
  const float* Wq = (const float*)d_in[2];
  const float* Wv = (const float*)d_in[3];
  const float* Wu = (const float*)d_in[4];
  float* out = (float*)d_out;

  const long SZ_X = 4096L * 512;
  const size_t NEED = 150994944;  // 144 MiB (we use 140; 180 verified previously)

  if (ws_size < NEED) {
    hipMemsetAsync(d_out, 0, (size_t)out_size * 4, stream);
    k_sentinel<<<1, 1, 0, stream>>>(out, (float)ws_size);
    return;
  }

  char* p = (char*)d_ws;
  unsigned short* Xbf  = (unsigned short*)p; p += SZ_X * 2;           //  4 MiB
  unsigned short* Wvut = (unsigned short*)p; p += 8L * 512 * 512 * 2; //  4 MiB [h][e][k]
  unsigned short* Gt   = (unsigned short*)p; p += 8L * 512 * 512 * 2; //  4 MiB [h][b'][a]
  unsigned short* T    = (unsigned short*)p; p += 4096L * 4096 * 2;   // 32 MiB [bt][h*512+b']
  unsigned short* Pb   = (unsigned short*)p; p += 4096L * 8192 * 2;   // 64 MiB [b][i][h*1024+j]
  unsigned short* VUt  = (unsigned short*)p;                          // 32 MiB [h*512+e][b*1024+j]
  float* Opart = (float*)T;  // 32 MiB alias: T dead after S-gemm; 4x[4096][512] fp32

  // L1: x convert + weight folds (fp32-direct staging), one launch
  k_wsetup<<<dim3(8, 288), 256, 0, stream>>>(x, Wq, Wk, Wv, Wu, Xbf, Gt, Wvut);

  // L2: T = X.Gt^T (17.2 GF) + VU^T = Wvut.X^T (17.2 GF), fused
  k_gemm_tv<<<dim3(8, 256), 256, 0, stream>>>(Xbf, Gt, Wvut, T, VUt);

  // L3: P[b][i][h*1024+j] = T.X^T (34.4 GF), B-operand = X (L2-tiny)
  k_gemm_s<<<dim3(8, 256), 256, 0, stream>>>(Xbf, T, Pb);

  // L4: softmax over each 1024-chunk of P, in place
  k_softmax_x<<<dim3(8, 1024), 256, 0, stream>>>(Pb);

  // L5: out partials = P . VU^T (strided-head B), plain fp32 stores
  k_gemm_out<<<dim3(8, 64), 256, 0, stream>>>(Pb, VUt, Opart);

  // L6: out = sum of 4 partials
  k_reduce<<<2048, 256, 0, stream>>>(Opart, out);
}